// Round 5
// baseline (193.000 us; speedup 1.0000x reference)
//
#include <hip/hip_runtime.h>
#include <math.h>

#define HID 128
#define TILE_R 64
#define TILE_P 32          // precompute row tile
#define XS_STRIDE 132      // fp32 staging stride (K1)
#define H0S_STRIDE 136     // bf16 LDS stride in shorts: 136*2B row = 68 dwords == 4 mod 32 banks
#define DELTA 0.05f        // per-score qualify margin (R3/R6-validated)
#define MAIN_GRID 1024     // 4 blocks/CU co-resident persistent main
#define LCAP 128           // per-block candidate cap (expected ~2)
#define GCAP 8192          // global candidate cap (expected ~2000)

typedef short bf16x8 __attribute__((ext_vector_type(8)));
typedef float f32x4 __attribute__((ext_vector_type(4)));

static __device__ __forceinline__ unsigned short f2bf(float f) {
    union { float f; unsigned u; } v; v.f = f;
    unsigned r = v.u + 0x7FFFu + ((v.u >> 16) & 1u);   // RNE
    return (unsigned short)(r >> 16);
}
static __device__ __forceinline__ float bflo(unsigned u) {
    union { unsigned u; float f; } v; v.u = u << 16; return v.f;
}
static __device__ __forceinline__ float bfhi(unsigned u) {
    union { unsigned u; float f; } v; v.u = u & 0xFFFF0000u; return v.f;
}

#define FMA4(avc, wv)                         \
    acc[r][0] = fmaf(avc, wv.x, acc[r][0]);   \
    acc[r][1] = fmaf(avc, wv.y, acc[r][1]);   \
    acc[r][2] = fmaf(avc, wv.z, acc[r][2]);   \
    acc[r][3] = fmaf(avc, wv.w, acc[r][3]);

static __device__ __forceinline__ void sm_merge(float& am, float& az, float& ass, int& ai,
                                                float bm, float bz, float bss, int bi)
{
    if (bm > am || (bm == am && bi < ai)) {
        float tm = am, tz = az, ts = ass; int ti = ai;
        am = bm; az = bz; ass = bss; ai = bi;
        bm = tm; bz = tz; bss = ts; bi = ti;
    }
    float f = expf(bm - am);
    az += bz * f;
    ass += (bss + (bm - am) * bz) * f;
}

// ---------------------------------------------------------------------------
// K1: g = x_graph @ W0[0:256] + b0 (fp32); Pbf = bf16 node partials;
//     W1T[n*128+k] = bf16(W1[k][n]).  Block 0 zeroes ncand + donecnt
//     (re-zeroed every graph replay; visible to K2 by stream order).
// ---------------------------------------------------------------------------
__global__ __launch_bounds__(256, 4) void precompute_kernel(
    const float* __restrict__ x_graph,
    const float* __restrict__ x_m,
    const float* __restrict__ x_job,
    const float* __restrict__ W0,
    const float* __restrict__ b0,
    const float* __restrict__ W1,
    float* __restrict__ g,
    unsigned short* __restrict__ Pbf,
    unsigned short* __restrict__ W1T,
    int* __restrict__ ncand,
    int* __restrict__ donecnt,
    int M, int J, int aTiles, int bTiles)
{
    const int t = threadIdx.x;
    const int bid = blockIdx.x;

    if (bid == 0) {
        if (t == 0) { *ncand = 0; *donecnt = 0; }   // reset counters each replay
        __shared__ float xg[2 * HID];
        if (t < HID) { xg[t] = x_graph[t]; xg[t + HID] = x_graph[t + HID]; }
        __syncthreads();
        if (t < HID) {
            float acc = b0[t];
            #pragma unroll 8
            for (int k = 0; k < 2 * HID; ++k)
                acc = fmaf(xg[k], W0[k * HID + t], acc);
            g[t] = acc;
        }
        return;
    }
    if (bid == 1 + aTiles + bTiles) {
        for (int e = t; e < HID * HID; e += 256) {
            int n = e >> 7, k = e & 127;
            W1T[e] = f2bf(W1[k * HID + n]);
        }
        return;
    }

    const int tb = bid - 1;
    const float* X;
    const float* W;
    int r0, nr, dstBase;
    if (tb < aTiles) {
        r0 = tb * TILE_P;
        nr = min(TILE_P, M - r0);
        X = x_m + (size_t)r0 * HID;
        W = W0 + 2 * HID * HID;
        dstBase = r0;
    } else {
        int jb = tb - aTiles;
        r0 = jb * TILE_P;
        nr = min(TILE_P, J - r0);
        X = x_job + (size_t)r0 * HID;
        W = W0 + 3 * HID * HID;
        dstBase = M + r0;
    }

    __shared__ float xs[TILE_P * XS_STRIDE];
    {
        int row = t >> 3;
        int e = t & 7;
        #pragma unroll
        for (int u = 0; u < 4; ++u) {
            int c = e * 16 + u * 4;
            float4 v = (row < nr) ? *(const float4*)(X + row * HID + c)
                                  : make_float4(0.f, 0.f, 0.f, 0.f);
            *(float4*)&xs[row * XS_STRIDE + c] = v;
        }
    }
    __syncthreads();

    const int w = t >> 6;
    const int l = t & 63;
    const int tc = l & 7;
    const int tr = l >> 3;
    const int c0 = w * 32 + tc * 4;

    float acc[4][4];
    #pragma unroll
    for (int r = 0; r < 4; ++r)
        #pragma unroll
        for (int c = 0; c < 4; ++c) acc[r][c] = 0.0f;

    #pragma unroll 2
    for (int k0 = 0; k0 < HID; k0 += 4) {
        float4 w0v = *(const float4*)(W + (k0 + 0) * HID + c0);
        float4 w1v = *(const float4*)(W + (k0 + 1) * HID + c0);
        float4 w2m = *(const float4*)(W + (k0 + 2) * HID + c0);
        float4 w3v = *(const float4*)(W + (k0 + 3) * HID + c0);
        #pragma unroll
        for (int r = 0; r < 4; ++r) {
            float4 a = *(const float4*)&xs[(r * 8 + tr) * XS_STRIDE + k0];
            FMA4(a.x, w0v)
            FMA4(a.y, w1v)
            FMA4(a.z, w2m)
            FMA4(a.w, w3v)
        }
    }

    #pragma unroll
    for (int r = 0; r < 4; ++r) {
        int row = r * 8 + tr;
        if (row < nr) {
            unsigned lo0 = (unsigned)f2bf(acc[r][0]) | ((unsigned)f2bf(acc[r][1]) << 16);
            unsigned lo1 = (unsigned)f2bf(acc[r][2]) | ((unsigned)f2bf(acc[r][3]) << 16);
            uint2 pk = make_uint2(lo0, lo1);
            *(uint2*)(Pbf + (size_t)(dstBase + row) * HID + c0) = pk;
        }
    }
}

// ---------------------------------------------------------------------------
// K2 (R17): persistent reg-B main + candidate harvest + LAST-DONE-BLOCK
//   finalize (no separate tail kernel -- R4 measured a near-empty 1-block
//   tail dispatch at 52us; tail latency, not throughput, dominates).
//   Arrival: R3-validated pattern (syncthreads drains stores; t0 release
//   fence + agent atomic; last block acquire fence). Finalize body is
//   VERBATIM R4 -> bit-identical outputs.
// ---------------------------------------------------------------------------
__global__ __launch_bounds__(256, 4) void main_kernel(
    const int* __restrict__ m_ids,
    const int* __restrict__ job_idx,
    const float* __restrict__ b1,
    const float* __restrict__ W2,
    const float* __restrict__ b2,
    const float* __restrict__ g,
    const unsigned short* __restrict__ Pbf,
    const unsigned short* __restrict__ W1T,
    const float* __restrict__ x_m,
    const float* __restrict__ x_job,
    const float* __restrict__ W0,
    const float* __restrict__ W1,
    float4* __restrict__ partials,
    int* __restrict__ candIdx,
    float* __restrict__ candS,
    int* __restrict__ ncand,
    int* __restrict__ donecnt,
    float* __restrict__ out,
    int N, int M, int tiles)
{
    __shared__ __align__(16) short h0s[TILE_R * H0S_STRIDE];
    __shared__ float sred[4 * TILE_R];
    __shared__ int lcand[LCAP];
    __shared__ float lcs[LCAP];
    __shared__ int lcnt;
    __shared__ int lastFlag;

    const int t = threadIdx.x;
    const int l = t & 63;
    const int w = t >> 6;
    const int quad = l >> 4;
    const int mrow = l & 15;

    if (t == 0) lcnt = 0;

    // ---- B fragments + epilogue constants: once per block ----
    bf16x8 bfr[2][4];
    {
        const unsigned short* wb = W1T + (size_t)(w * 32 + mrow) * HID + quad * 8;
        #pragma unroll
        for (int nt = 0; nt < 2; ++nt)
            #pragma unroll
            for (int kc = 0; kc < 4; ++kc)
                bfr[nt][kc] = *(const bf16x8*)(wb + nt * 16 * HID + kc * 32);
    }
    const float b1v0 = b1[w * 32 + mrow];
    const float b1v1 = b1[w * 32 + 16 + mrow];
    const float w2v0 = W2[w * 32 + mrow];
    const float w2v1 = W2[w * 32 + 16 + mrow];
    const float b2v = b2[0];

    float rmax = -1e30f;   // block-running max (meaningful in wave 0)

    for (int tile = blockIdx.x; tile < tiles; tile += MAIN_GRID) {
        const int row0 = tile * TILE_R;

        // ---- stage h0 (bf16): thread t -> row t/4, 32-col quarter t%4 ----
        {
            int row = t >> 2;
            int q = t & 3;
            int grow = row0 + row;
            int gr = (grow < N) ? grow : (N - 1);
            int m = m_ids[gr];
            int j = job_idx[gr];
            const unsigned short* pm = Pbf + (size_t)m * HID + q * 32;
            const unsigned short* pj = Pbf + (size_t)(M + j) * HID + q * 32;
            const float* gp = g + q * 32;
            short* dst = &h0s[row * H0S_STRIDE + q * 32];
            #pragma unroll
            for (int u = 0; u < 4; ++u) {
                uint4 mv = *(const uint4*)(pm + u * 8);
                uint4 jv = *(const uint4*)(pj + u * 8);
                float4 g0 = *(const float4*)(gp + u * 8);
                float4 g1 = *(const float4*)(gp + u * 8 + 4);
                float h0v = fmaxf(bflo(mv.x) + bflo(jv.x) + g0.x, 0.f);
                float h1v = fmaxf(bfhi(mv.x) + bfhi(jv.x) + g0.y, 0.f);
                float h2v = fmaxf(bflo(mv.y) + bflo(jv.y) + g0.z, 0.f);
                float h3v = fmaxf(bfhi(mv.y) + bfhi(jv.y) + g0.w, 0.f);
                float h4v = fmaxf(bflo(mv.z) + bflo(jv.z) + g1.x, 0.f);
                float h5v = fmaxf(bfhi(mv.z) + bfhi(jv.z) + g1.y, 0.f);
                float h6v = fmaxf(bflo(mv.w) + bflo(jv.w) + g1.z, 0.f);
                float h7v = fmaxf(bfhi(mv.w) + bfhi(jv.w) + g1.w, 0.f);
                uint4 pk;
                pk.x = (unsigned)f2bf(h0v) | ((unsigned)f2bf(h1v) << 16);
                pk.y = (unsigned)f2bf(h2v) | ((unsigned)f2bf(h3v) << 16);
                pk.z = (unsigned)f2bf(h4v) | ((unsigned)f2bf(h5v) << 16);
                pk.w = (unsigned)f2bf(h6v) | ((unsigned)f2bf(h7v) << 16);
                *(uint4*)(dst + u * 8) = pk;
            }
        }
        __syncthreads();                       // barrier 1: h0s ready

        // ---- MFMA: 4 m-tiles x 2 n-tiles; A from LDS, B from registers ----
        f32x4 acc[4][2];
        #pragma unroll
        for (int mt = 0; mt < 4; ++mt) {
            f32x4 z = {0.f, 0.f, 0.f, 0.f};
            acc[mt][0] = z;
            acc[mt][1] = z;
        }
        #pragma unroll
        for (int mt = 0; mt < 4; ++mt) {
            const short* ab = &h0s[(mt * 16 + mrow) * H0S_STRIDE + quad * 8];
            #pragma unroll
            for (int kc = 0; kc < 4; ++kc) {
                bf16x8 af = *(const bf16x8*)(ab + kc * 32);
                acc[mt][0] = __builtin_amdgcn_mfma_f32_16x16x32_bf16(af, bfr[0][kc], acc[mt][0], 0, 0, 0);
                acc[mt][1] = __builtin_amdgcn_mfma_f32_16x16x32_bf16(af, bfr[1][kc], acc[mt][1], 0, 0, 0);
            }
        }

        // ---- epilogue: relu+b1, dot W2; reduce over 16 cols (mrow lanes) ----
        #pragma unroll
        for (int mt = 0; mt < 4; ++mt) {
            float p[4];
            #pragma unroll
            for (int i = 0; i < 4; ++i) {
                p[i] = fmaxf(acc[mt][0][i] + b1v0, 0.f) * w2v0
                     + fmaxf(acc[mt][1][i] + b1v1, 0.f) * w2v1;
            }
            #pragma unroll
            for (int off = 1; off < 16; off <<= 1) {
                #pragma unroll
                for (int i = 0; i < 4; ++i)
                    p[i] += __shfl_xor(p[i], off);
            }
            if (mrow == 0) {
                int rb = mt * 16 + quad * 4;
                sred[w * TILE_R + rb + 0] = p[0];
                sred[w * TILE_R + rb + 1] = p[1];
                sred[w * TILE_R + rb + 2] = p[2];
                sred[w * TILE_R + rb + 3] = p[3];
            }
        }
        __syncthreads();                       // barrier 2: sred ready; h0s free

        // ---- wave 0: combine col-groups, softmax partial, candidates ----
        if (t < 64) {
            int grow = row0 + t;
            bool valid = grow < N;
            float s = sred[t] + sred[64 + t] + sred[128 + t] + sred[192 + t] + b2v;
            if (!valid) s = -1e30f;

            float mmax = s;
            int midx = grow;
            #pragma unroll
            for (int off = 1; off < 64; off <<= 1) {
                float om = __shfl_xor(mmax, off);
                int oi = __shfl_xor(midx, off);
                if (om > mmax || (om == mmax && oi < midx)) { mmax = om; midx = oi; }
            }
            float d = s - mmax;
            float e = expf(d);
            float z = e;
            float ss = d * e;
            #pragma unroll
            for (int off = 1; off < 64; off <<= 1) {
                z += __shfl_xor(z, off);
                ss += __shfl_xor(ss, off);
            }
            if (t == 0) partials[tile] = make_float4(mmax, z, ss, (float)midx);

            // candidate harvest: superset of {s >= gmax-DELTA} (rmax<=gmax)
            rmax = fmaxf(rmax, mmax);
            unsigned long long qm = __ballot(valid && (s >= rmax - DELTA));
            if (qm) {
                int cnt = __popcll(qm);
                int rank = __popcll(qm & ((1ull << t) - 1ull));
                int lb;
                if (t == 0) lb = atomicAdd(&lcnt, cnt);   // LDS atomic (wave 0 only)
                lb = __shfl(lb, 0);
                if ((qm >> t) & 1ull) {
                    int p = lb + rank;
                    if (p < LCAP) { lcand[p] = grow; lcs[p] = s; }
                }
            }
        }
        // sred reads above precede next iteration's barrier 1; next writes
        // happen after it -> no WAR hazard. lcand/lcnt touched only by wave 0.
    }

    // ---- block-end flush: one staggered device atomic, burst copy ----
    if (t < 64) {
        int cnt = min(lcnt, LCAP);
        if (cnt > 0) {
            int gb;
            if (t == 0) gb = atomicAdd(ncand, cnt);       // device-scope
            gb = __shfl(gb, 0);
            for (int c = t; c < cnt; c += 64) {
                int p = gb + c;
                if (p < GCAP) { candIdx[p] = lcand[c]; candS[p] = lcs[c]; }
            }
        }
    }

    // ---- arrival: last-done block runs finalize (R3-validated pattern) ----
    __syncthreads();            // drain all waves' stores (vmcnt0 at barrier)
    if (t == 0) {
        __threadfence();        // release: publish partials/cand* device-wide
        int v = __hip_atomic_fetch_add(donecnt, 1, __ATOMIC_ACQ_REL,
                                       __HIP_MEMORY_SCOPE_AGENT);
        lastFlag = (v == (int)gridDim.x - 1);
    }
    __syncthreads();
    if (!lastFlag) return;
    __threadfence();            // acquire: see all other blocks' writes

    // ================= finalize (VERBATIM R4 body, last block only) ========
    {
        __shared__ float4 wred[4];
        __shared__ int widx[4];
        __shared__ int surv[LCAP];
        __shared__ int scnt;
        __shared__ float frs[4];
        __shared__ int fri[4];

        float fm = -1e30f, fz = 0.f, fss = 0.f;
        int fidx = 0x7fffffff;
        for (int i = t; i < tiles; i += 256) {
            float4 p = partials[i];
            sm_merge(fm, fz, fss, fidx, p.x, p.y, p.z, (int)p.w);
        }
        #pragma unroll
        for (int off = 1; off < 64; off <<= 1) {
            float om = __shfl_xor(fm, off);
            float oz = __shfl_xor(fz, off);
            float os = __shfl_xor(fss, off);
            int oi = __shfl_xor(fidx, off);
            sm_merge(fm, fz, fss, fidx, om, oz, os, oi);
        }
        if (l == 0) { wred[w] = make_float4(fm, fz, fss, 0.f); widx[w] = fidx; }
        if (t == 0) scnt = 0;
        __syncthreads();

        // true global cut (gmax = max over per-tile mmax)
        const float gm = fmaxf(fmaxf(wred[0].x, wred[1].x), fmaxf(wred[2].x, wred[3].x));
        const float cut = gm - DELTA;

        // ---- survivor filter: parallel coalesced pass over candidate list ----
        const int nc = min(*ncand, GCAP);
        for (int c = t; c < nc; c += 256) {
            if (candS[c] >= cut) {
                int p = atomicAdd(&scnt, 1);
                if (p < LCAP) surv[p] = candIdx[c];
            }
        }
        __syncthreads();
        const int ns = min(scnt, LCAP);

        // ---- exact fp32 rescore of survivors (verbatim old scan body) ----
        float bs = -1e30f;
        int bi = 0x7fffffff;
        for (int c = w; c < ns; c += 4) {
            int gr = surv[c];
            int mm = m_ids[gr];
            int jj = job_idx[gr];
            const float* xm = x_m + (size_t)mm * HID;
            const float* xj = x_job + (size_t)jj * HID;
            const float* wm = W0 + 2 * HID * HID;
            const float* wj = W0 + 3 * HID * HID;
            float a0 = g[l], a1 = g[l + 64];
            for (int k = 0; k < HID; ++k) {
                float xmk = xm[k];
                float xjk = xj[k];
                a0 = fmaf(xmk, wm[k * HID + l], a0);
                a1 = fmaf(xmk, wm[k * HID + l + 64], a1);
                a0 = fmaf(xjk, wj[k * HID + l], a0);
                a1 = fmaf(xjk, wj[k * HID + l + 64], a1);
            }
            a0 = fmaxf(a0, 0.f);
            a1 = fmaxf(a1, 0.f);
            float acc0 = 0.f, acc1 = 0.f;
            for (int k = 0; k < 64; ++k) {
                float h = __shfl(a0, k);
                acc0 = fmaf(h, W1[k * HID + l], acc0);
                acc1 = fmaf(h, W1[k * HID + l + 64], acc1);
            }
            for (int k = 0; k < 64; ++k) {
                float h = __shfl(a1, k);
                acc0 = fmaf(h, W1[(k + 64) * HID + l], acc0);
                acc1 = fmaf(h, W1[(k + 64) * HID + l + 64], acc1);
            }
            float p = fmaxf(acc0 + b1[l], 0.f) * W2[l]
                    + fmaxf(acc1 + b1[l + 64], 0.f) * W2[l + 64];
            #pragma unroll
            for (int off = 1; off < 64; off <<= 1)
                p += __shfl_xor(p, off);
            float s = p + b2[0];
            if (s > bs || (s == bs && gr < bi)) { bs = s; bi = gr; }
        }
        if (l == 0) { frs[w] = bs; fri[w] = bi; }
        __syncthreads();

        if (t == 0) {
            for (int i = 1; i < 4; ++i)
                sm_merge(fm, fz, fss, fidx, wred[i].x, wred[i].y, wred[i].z, widx[i]);
            for (int i = 1; i < 4; ++i)
                if (frs[i] > bs || (frs[i] == bs && fri[i] < bi)) { bs = frs[i]; bi = fri[i]; }
            float logZ = logf(fz);
            out[0] = (float)bi;              // exact argmax
            out[1] = expf(bs - fm) / fz;     // probs[idx]
            out[2] = (bs - fm) - logZ;       // logp[idx]
            out[3] = logZ - fss / fz;        // entropy
        }
    }
}

// ---------------------------------------------------------------------------
extern "C" void kernel_launch(void* const* d_in, const int* in_sizes, int n_in,
                              void* d_out, int out_size, void* d_ws, size_t ws_size,
                              hipStream_t stream)
{
    const float* x_graph = (const float*)d_in[0];
    const float* x_m     = (const float*)d_in[1];
    const float* x_job   = (const float*)d_in[2];
    const int*   m_ids   = (const int*)d_in[3];
    const int*   job_idx = (const int*)d_in[4];
    const float* W0      = (const float*)d_in[5];
    const float* b0      = (const float*)d_in[6];
    const float* W1      = (const float*)d_in[7];
    const float* b1      = (const float*)d_in[8];
    const float* W2      = (const float*)d_in[9];
    const float* b2      = (const float*)d_in[10];
    float* out = (float*)d_out;

    const int N = in_sizes[3];
    const int M = in_sizes[1] / HID;
    const int J = in_sizes[2] / HID;

    const int tiles = (N + TILE_R - 1) / TILE_R;         // 3125
    const int aTiles = (M + TILE_P - 1) / TILE_P;        // 32
    const int bTiles = (J + TILE_P - 1) / TILE_P;        // 157

    // ws layout (segments 16-B aligned):
    float* ws = (float*)d_ws;
    float* g = ws;                                        // 128 f
    float4* partials = (float4*)(g + HID);                // tiles f4
    int* candIdx = (int*)(partials + tiles);              // GCAP i
    float* candS = (float*)(candIdx + GCAP);              // GCAP f
    int* ncand = (int*)(candS + GCAP);                    // 1 i
    int* donecnt = ncand + 1;                             // 1 i (+pad 2)
    unsigned short* W1T = (unsigned short*)(ncand + 4);   // HID*HID shorts
    unsigned short* Pbf = W1T + HID * HID;                // (M+J)*HID shorts

    precompute_kernel<<<1 + aTiles + bTiles + 1, 256, 0, stream>>>(
        x_graph, x_m, x_job, W0, b0, W1, g, Pbf, W1T, ncand, donecnt,
        M, J, aTiles, bTiles);
    main_kernel<<<MAIN_GRID, 256, 0, stream>>>(
        m_ids, job_idx, b1, W2, b2, g, Pbf, W1T, x_m, x_job, W0, W1,
        partials, candIdx, candS, ncand, donecnt, out, N, M, tiles);
}

// Round 6
// 175.468 us; speedup vs baseline: 1.0999x; 1.0999x over previous
//
#include <hip/hip_runtime.h>
#include <math.h>

#define HID 128
#define TILE_R 64
#define TILE_P 32          // precompute row tile
#define XS_STRIDE 132      // fp32 staging stride (K1)
#define H0S_STRIDE 136     // bf16 LDS stride in shorts: 136*2B row = 68 dwords == 4 mod 32 banks
#define DELTA 0.05f        // per-score qualify margin (R3/R6-validated)
#define MAIN_GRID 1024     // 4 blocks/CU co-resident persistent main
#define LCAP 128           // per-block candidate cap
#define GCAP 8192          // global candidate cap

typedef short bf16x8 __attribute__((ext_vector_type(8)));
typedef float f32x4 __attribute__((ext_vector_type(4)));

static __device__ __forceinline__ unsigned short f2bf(float f) {
    union { float f; unsigned u; } v; v.f = f;
    unsigned r = v.u + 0x7FFFu + ((v.u >> 16) & 1u);   // RNE
    return (unsigned short)(r >> 16);
}
static __device__ __forceinline__ float bflo(unsigned u) {
    union { unsigned u; float f; } v; v.u = u << 16; return v.f;
}
static __device__ __forceinline__ float bfhi(unsigned u) {
    union { unsigned u; float f; } v; v.u = u & 0xFFFF0000u; return v.f;
}
// monotone float<->uint order map (for atomicMax on float scores)
static __device__ __forceinline__ unsigned f2ord(float f) {
    unsigned b = __float_as_uint(f);
    return (b & 0x80000000u) ? ~b : (b | 0x80000000u);
}
static __device__ __forceinline__ float ord2f(unsigned u) {
    return __uint_as_float((u & 0x80000000u) ? (u ^ 0x80000000u) : ~u);
}

#define FMA4(avc, wv)                         \
    acc[r][0] = fmaf(avc, wv.x, acc[r][0]);   \
    acc[r][1] = fmaf(avc, wv.y, acc[r][1]);   \
    acc[r][2] = fmaf(avc, wv.z, acc[r][2]);   \
    acc[r][3] = fmaf(avc, wv.w, acc[r][3]);

static __device__ __forceinline__ void sm_merge(float& am, float& az, float& ass, int& ai,
                                                float bm, float bz, float bss, int bi)
{
    if (bm > am || (bm == am && bi < ai)) {
        float tm = am, tz = az, ts = ass; int ti = ai;
        am = bm; az = bz; ass = bss; ai = bi;
        bm = tm; bz = tz; bss = ts; bi = ti;
    }
    float f = expf(bm - am);
    az += bz * f;
    ass += (bss + (bm - am) * bz) * f;
}

// ---------------------------------------------------------------------------
// K1: g = x_graph @ W0[0:256] + b0 (fp32); Pbf = bf16 node partials;
//     W1T[n*128+k] = bf16(W1[k][n]).  Block 0 zeroes ncand/donecnt/gmaxU
//     (re-zeroed every graph replay; visible to K2 by stream order).
// ---------------------------------------------------------------------------
__global__ __launch_bounds__(256, 4) void precompute_kernel(
    const float* __restrict__ x_graph,
    const float* __restrict__ x_m,
    const float* __restrict__ x_job,
    const float* __restrict__ W0,
    const float* __restrict__ b0,
    const float* __restrict__ W1,
    float* __restrict__ g,
    unsigned short* __restrict__ Pbf,
    unsigned short* __restrict__ W1T,
    int* __restrict__ ncand,
    int* __restrict__ donecnt,
    unsigned* __restrict__ gmaxU,
    int M, int J, int aTiles, int bTiles)
{
    const int t = threadIdx.x;
    const int bid = blockIdx.x;

    if (bid == 0) {
        if (t == 0) { *ncand = 0; *donecnt = 0; *gmaxU = 0u; }  // reset each replay
        __shared__ float xg[2 * HID];
        if (t < HID) { xg[t] = x_graph[t]; xg[t + HID] = x_graph[t + HID]; }
        __syncthreads();
        if (t < HID) {
            float acc = b0[t];
            #pragma unroll 8
            for (int k = 0; k < 2 * HID; ++k)
                acc = fmaf(xg[k], W0[k * HID + t], acc);
            g[t] = acc;
        }
        return;
    }
    if (bid == 1 + aTiles + bTiles) {
        for (int e = t; e < HID * HID; e += 256) {
            int n = e >> 7, k = e & 127;
            W1T[e] = f2bf(W1[k * HID + n]);
        }
        return;
    }

    const int tb = bid - 1;
    const float* X;
    const float* W;
    int r0, nr, dstBase;
    if (tb < aTiles) {
        r0 = tb * TILE_P;
        nr = min(TILE_P, M - r0);
        X = x_m + (size_t)r0 * HID;
        W = W0 + 2 * HID * HID;
        dstBase = r0;
    } else {
        int jb = tb - aTiles;
        r0 = jb * TILE_P;
        nr = min(TILE_P, J - r0);
        X = x_job + (size_t)r0 * HID;
        W = W0 + 3 * HID * HID;
        dstBase = M + r0;
    }

    __shared__ float xs[TILE_P * XS_STRIDE];
    {
        int row = t >> 3;
        int e = t & 7;
        #pragma unroll
        for (int u = 0; u < 4; ++u) {
            int c = e * 16 + u * 4;
            float4 v = (row < nr) ? *(const float4*)(X + row * HID + c)
                                  : make_float4(0.f, 0.f, 0.f, 0.f);
            *(float4*)&xs[row * XS_STRIDE + c] = v;
        }
    }
    __syncthreads();

    const int w = t >> 6;
    const int l = t & 63;
    const int tc = l & 7;
    const int tr = l >> 3;
    const int c0 = w * 32 + tc * 4;

    float acc[4][4];
    #pragma unroll
    for (int r = 0; r < 4; ++r)
        #pragma unroll
        for (int c = 0; c < 4; ++c) acc[r][c] = 0.0f;

    #pragma unroll 2
    for (int k0 = 0; k0 < HID; k0 += 4) {
        float4 w0v = *(const float4*)(W + (k0 + 0) * HID + c0);
        float4 w1v = *(const float4*)(W + (k0 + 1) * HID + c0);
        float4 w2m = *(const float4*)(W + (k0 + 2) * HID + c0);
        float4 w3v = *(const float4*)(W + (k0 + 3) * HID + c0);
        #pragma unroll
        for (int r = 0; r < 4; ++r) {
            float4 a = *(const float4*)&xs[(r * 8 + tr) * XS_STRIDE + k0];
            FMA4(a.x, w0v)
            FMA4(a.y, w1v)
            FMA4(a.z, w2m)
            FMA4(a.w, w3v)
        }
    }

    #pragma unroll
    for (int r = 0; r < 4; ++r) {
        int row = r * 8 + tr;
        if (row < nr) {
            unsigned lo0 = (unsigned)f2bf(acc[r][0]) | ((unsigned)f2bf(acc[r][1]) << 16);
            unsigned lo1 = (unsigned)f2bf(acc[r][2]) | ((unsigned)f2bf(acc[r][3]) << 16);
            uint2 pk = make_uint2(lo0, lo1);
            *(uint2*)(Pbf + (size_t)(dstBase + row) * HID + c0) = pk;
        }
    }
}

// ---------------------------------------------------------------------------
// K2 (R18): persistent reg-B main + shared-gmax candidate harvest +
//   PARALLEL rescore-at-harvest + last-done-block tiny finalize.
//   R5 measured: one-block finalize tail ~60us (serial 128-step shfl-dot
//   per survivor). Fix: each block exact-rescores ITS OWN candidates with
//   4 waves during the parallel phase; candS holds EXACT scores; tail is
//   just {partials merge + parallel max over candidates} (~2-3us).
//   Superset argument: harvest cut (running max <= final gmax) keeps every
//   row with s_bf16 >= gmax_bf16-DELTA; under the validated DELTA band the
//   exact argmax+ties lie in that set, so exact-argmax over the superset
//   is IDENTICAL to the old filter+rescore result (same tie-break).
//   Shared running max (atomicMax, monotone-uint) tightens the cut with
//   other blocks' progress -- any stale read <= gmax keeps the superset.
// ---------------------------------------------------------------------------
__global__ __launch_bounds__(256, 4) void main_kernel(
    const int* __restrict__ m_ids,
    const int* __restrict__ job_idx,
    const float* __restrict__ b1,
    const float* __restrict__ W2,
    const float* __restrict__ b2,
    const float* __restrict__ g,
    const unsigned short* __restrict__ Pbf,
    const unsigned short* __restrict__ W1T,
    const float* __restrict__ x_m,
    const float* __restrict__ x_job,
    const float* __restrict__ W0,
    const float* __restrict__ W1,
    float4* __restrict__ partials,
    int* __restrict__ candIdx,
    float* __restrict__ candS,
    int* __restrict__ ncand,
    int* __restrict__ donecnt,
    unsigned* __restrict__ gmaxU,
    float* __restrict__ out,
    int N, int M, int tiles)
{
    __shared__ __align__(16) short h0s[TILE_R * H0S_STRIDE];
    __shared__ float sred[4 * TILE_R];
    __shared__ int lcand[LCAP];
    __shared__ float lcs[LCAP];
    __shared__ int lcnt;
    __shared__ int lastFlag;

    const int t = threadIdx.x;
    const int l = t & 63;
    const int w = t >> 6;
    const int quad = l >> 4;
    const int mrow = l & 15;

    if (t == 0) lcnt = 0;

    // ---- B fragments + epilogue constants: once per block ----
    bf16x8 bfr[2][4];
    {
        const unsigned short* wb = W1T + (size_t)(w * 32 + mrow) * HID + quad * 8;
        #pragma unroll
        for (int nt = 0; nt < 2; ++nt)
            #pragma unroll
            for (int kc = 0; kc < 4; ++kc)
                bfr[nt][kc] = *(const bf16x8*)(wb + nt * 16 * HID + kc * 32);
    }
    const float b1v0 = b1[w * 32 + mrow];
    const float b1v1 = b1[w * 32 + 16 + mrow];
    const float w2v0 = W2[w * 32 + mrow];
    const float w2v1 = W2[w * 32 + 16 + mrow];
    const float b2v = b2[0];

    float rmax = -1e30f;   // running max known to this block (wave 0)

    for (int tile = blockIdx.x; tile < tiles; tile += MAIN_GRID) {
        const int row0 = tile * TILE_R;

        // ---- stage h0 (bf16): thread t -> row t/4, 32-col quarter t%4 ----
        {
            int row = t >> 2;
            int q = t & 3;
            int grow = row0 + row;
            int gr = (grow < N) ? grow : (N - 1);
            int m = m_ids[gr];
            int j = job_idx[gr];
            const unsigned short* pm = Pbf + (size_t)m * HID + q * 32;
            const unsigned short* pj = Pbf + (size_t)(M + j) * HID + q * 32;
            const float* gp = g + q * 32;
            short* dst = &h0s[row * H0S_STRIDE + q * 32];
            #pragma unroll
            for (int u = 0; u < 4; ++u) {
                uint4 mv = *(const uint4*)(pm + u * 8);
                uint4 jv = *(const uint4*)(pj + u * 8);
                float4 g0 = *(const float4*)(gp + u * 8);
                float4 g1 = *(const float4*)(gp + u * 8 + 4);
                float h0v = fmaxf(bflo(mv.x) + bflo(jv.x) + g0.x, 0.f);
                float h1v = fmaxf(bfhi(mv.x) + bfhi(jv.x) + g0.y, 0.f);
                float h2v = fmaxf(bflo(mv.y) + bflo(jv.y) + g0.z, 0.f);
                float h3v = fmaxf(bfhi(mv.y) + bfhi(jv.y) + g0.w, 0.f);
                float h4v = fmaxf(bflo(mv.z) + bflo(jv.z) + g1.x, 0.f);
                float h5v = fmaxf(bfhi(mv.z) + bfhi(jv.z) + g1.y, 0.f);
                float h6v = fmaxf(bflo(mv.w) + bflo(jv.w) + g1.z, 0.f);
                float h7v = fmaxf(bfhi(mv.w) + bfhi(jv.w) + g1.w, 0.f);
                uint4 pk;
                pk.x = (unsigned)f2bf(h0v) | ((unsigned)f2bf(h1v) << 16);
                pk.y = (unsigned)f2bf(h2v) | ((unsigned)f2bf(h3v) << 16);
                pk.z = (unsigned)f2bf(h4v) | ((unsigned)f2bf(h5v) << 16);
                pk.w = (unsigned)f2bf(h6v) | ((unsigned)f2bf(h7v) << 16);
                *(uint4*)(dst + u * 8) = pk;
            }
        }
        __syncthreads();                       // barrier 1: h0s ready

        // ---- MFMA: 4 m-tiles x 2 n-tiles; A from LDS, B from registers ----
        f32x4 acc[4][2];
        #pragma unroll
        for (int mt = 0; mt < 4; ++mt) {
            f32x4 z = {0.f, 0.f, 0.f, 0.f};
            acc[mt][0] = z;
            acc[mt][1] = z;
        }
        #pragma unroll
        for (int mt = 0; mt < 4; ++mt) {
            const short* ab = &h0s[(mt * 16 + mrow) * H0S_STRIDE + quad * 8];
            #pragma unroll
            for (int kc = 0; kc < 4; ++kc) {
                bf16x8 af = *(const bf16x8*)(ab + kc * 32);
                acc[mt][0] = __builtin_amdgcn_mfma_f32_16x16x32_bf16(af, bfr[0][kc], acc[mt][0], 0, 0, 0);
                acc[mt][1] = __builtin_amdgcn_mfma_f32_16x16x32_bf16(af, bfr[1][kc], acc[mt][1], 0, 0, 0);
            }
        }

        // ---- epilogue: relu+b1, dot W2; reduce over 16 cols (mrow lanes) ----
        #pragma unroll
        for (int mt = 0; mt < 4; ++mt) {
            float p[4];
            #pragma unroll
            for (int i = 0; i < 4; ++i) {
                p[i] = fmaxf(acc[mt][0][i] + b1v0, 0.f) * w2v0
                     + fmaxf(acc[mt][1][i] + b1v1, 0.f) * w2v1;
            }
            #pragma unroll
            for (int off = 1; off < 16; off <<= 1) {
                #pragma unroll
                for (int i = 0; i < 4; ++i)
                    p[i] += __shfl_xor(p[i], off);
            }
            if (mrow == 0) {
                int rb = mt * 16 + quad * 4;
                sred[w * TILE_R + rb + 0] = p[0];
                sred[w * TILE_R + rb + 1] = p[1];
                sred[w * TILE_R + rb + 2] = p[2];
                sred[w * TILE_R + rb + 3] = p[3];
            }
        }
        __syncthreads();                       // barrier 2: sred ready; h0s free

        // ---- wave 0: combine col-groups, softmax partial, candidates ----
        if (t < 64) {
            int grow = row0 + t;
            bool valid = grow < N;
            float s = sred[t] + sred[64 + t] + sred[128 + t] + sred[192 + t] + b2v;
            if (!valid) s = -1e30f;

            float mmax = s;
            int midx = grow;
            #pragma unroll
            for (int off = 1; off < 64; off <<= 1) {
                float om = __shfl_xor(mmax, off);
                int oi = __shfl_xor(midx, off);
                if (om > mmax || (om == mmax && oi < midx)) { mmax = om; midx = oi; }
            }
            float d = s - mmax;
            float e = expf(d);
            float z = e;
            float ss = d * e;
            #pragma unroll
            for (int off = 1; off < 64; off <<= 1) {
                z += __shfl_xor(z, off);
                ss += __shfl_xor(ss, off);
            }
            if (t == 0) partials[tile] = make_float4(mmax, z, ss, (float)midx);

            // shared running max: publish tile max, learn others' progress.
            // any value here is <= final gmax_bf16 -> superset guarantee holds.
            if (t == 0) {
                unsigned old = atomicMax(gmaxU, f2ord(mmax));     // device-scope
                rmax = fmaxf(fmaxf(rmax, mmax), ord2f(old));      // ord2f(0)=NaN: fmaxf ignores
            }
            rmax = __shfl(rmax, 0);

            // candidate harvest: superset of {s >= gmax-DELTA}
            unsigned long long qm = __ballot(valid && (s >= rmax - DELTA));
            if (qm) {
                int cnt = __popcll(qm);
                int rank = __popcll(qm & ((1ull << t) - 1ull));
                int lb;
                if (t == 0) lb = atomicAdd(&lcnt, cnt);   // LDS atomic (wave 0 only)
                lb = __shfl(lb, 0);
                if ((qm >> t) & 1ull) {
                    int p = lb + rank;
                    if (p < LCAP) lcand[p] = grow;
                }
            }
        }
        // sred reads above precede next iteration's barrier 1; next writes
        // happen after it -> no WAR hazard. lcand/lcnt touched only by wave 0.
    }

    // ---- R18: exact fp32 rescore of OWN candidates, all 4 waves ----
    __syncthreads();                       // lcand/lcnt (wave 0) -> all waves
    {
        const int cnt = min(lcnt, LCAP);
        for (int c = w; c < cnt; c += 4) {
            int gr = lcand[c];
            int mm = m_ids[gr];
            int jj = job_idx[gr];
            const float* xm = x_m + (size_t)mm * HID;
            const float* xj = x_job + (size_t)jj * HID;
            const float* wm = W0 + 2 * HID * HID;
            const float* wj = W0 + 3 * HID * HID;
            float a0 = g[l], a1 = g[l + 64];
            for (int k = 0; k < HID; ++k) {
                float xmk = xm[k];
                float xjk = xj[k];
                a0 = fmaf(xmk, wm[k * HID + l], a0);
                a1 = fmaf(xmk, wm[k * HID + l + 64], a1);
                a0 = fmaf(xjk, wj[k * HID + l], a0);
                a1 = fmaf(xjk, wj[k * HID + l + 64], a1);
            }
            a0 = fmaxf(a0, 0.f);
            a1 = fmaxf(a1, 0.f);
            float acc0 = 0.f, acc1 = 0.f;
            for (int k = 0; k < 64; ++k) {
                float h = __shfl(a0, k);
                acc0 = fmaf(h, W1[k * HID + l], acc0);
                acc1 = fmaf(h, W1[k * HID + l + 64], acc1);
            }
            for (int k = 0; k < 64; ++k) {
                float h = __shfl(a1, k);
                acc0 = fmaf(h, W1[(k + 64) * HID + l], acc0);
                acc1 = fmaf(h, W1[(k + 64) * HID + l + 64], acc1);
            }
            float p = fmaxf(acc0 + b1[l], 0.f) * W2[l]
                    + fmaxf(acc1 + b1[l + 64], 0.f) * W2[l + 64];
            #pragma unroll
            for (int off = 1; off < 64; off <<= 1)
                p += __shfl_xor(p, off);
            if (l == 0) lcs[c] = p + b2v;     // EXACT score
        }
    }
    __syncthreads();                       // lcs visible to flusher

    // ---- block-end flush: one staggered device atomic, burst copy ----
    if (t < 64) {
        int cnt = min(lcnt, LCAP);
        if (cnt > 0) {
            int gb;
            if (t == 0) gb = atomicAdd(ncand, cnt);       // device-scope
            gb = __shfl(gb, 0);
            for (int c = t; c < cnt; c += 64) {
                int p = gb + c;
                if (p < GCAP) { candIdx[p] = lcand[c]; candS[p] = lcs[c]; }
            }
        }
    }

    // ---- arrival: last-done block runs the (now tiny) finalize ----
    __syncthreads();            // drain all waves' stores
    if (t == 0) {
        __threadfence();        // release: publish partials/cand* device-wide
        int v = __hip_atomic_fetch_add(donecnt, 1, __ATOMIC_ACQ_REL,
                                       __HIP_MEMORY_SCOPE_AGENT);
        lastFlag = (v == (int)gridDim.x - 1);
    }
    __syncthreads();
    if (!lastFlag) return;
    __threadfence();            // acquire: see all other blocks' writes

    // ================= finalize: merge partials + max over exact cands ====
    {
        __shared__ float4 wred[4];
        __shared__ int widx[4];
        __shared__ float frs[4];
        __shared__ int fri[4];

        float fm = -1e30f, fz = 0.f, fss = 0.f;
        int fidx = 0x7fffffff;
        for (int i = t; i < tiles; i += 256) {
            float4 p = partials[i];
            sm_merge(fm, fz, fss, fidx, p.x, p.y, p.z, (int)p.w);
        }
        #pragma unroll
        for (int off = 1; off < 64; off <<= 1) {
            float om = __shfl_xor(fm, off);
            float oz = __shfl_xor(fz, off);
            float os = __shfl_xor(fss, off);
            int oi = __shfl_xor(fidx, off);
            sm_merge(fm, fz, fss, fidx, om, oz, os, oi);
        }
        if (l == 0) { wred[w] = make_float4(fm, fz, fss, 0.f); widx[w] = fidx; }

        // exact argmax over candidate superset (identical winner/bs to the
        // old filter+rescore path -- see R18 header comment)
        float bs = -1e30f;
        int bi = 0x7fffffff;
        const int nc = min(*ncand, GCAP);
        for (int c = t; c < nc; c += 256) {
            float s = candS[c];
            int gi = candIdx[c];
            if (s > bs || (s == bs && gi < bi)) { bs = s; bi = gi; }
        }
        #pragma unroll
        for (int off = 1; off < 64; off <<= 1) {
            float os = __shfl_xor(bs, off);
            int oi = __shfl_xor(bi, off);
            if (os > bs || (os == bs && oi < bi)) { bs = os; bi = oi; }
        }
        if (l == 0) { frs[w] = bs; fri[w] = bi; }
        __syncthreads();

        if (t == 0) {
            for (int i = 1; i < 4; ++i)
                sm_merge(fm, fz, fss, fidx, wred[i].x, wred[i].y, wred[i].z, widx[i]);
            for (int i = 1; i < 4; ++i)
                if (frs[i] > bs || (frs[i] == bs && fri[i] < bi)) { bs = frs[i]; bi = fri[i]; }
            float logZ = logf(fz);
            out[0] = (float)bi;              // exact argmax
            out[1] = expf(bs - fm) / fz;     // probs[idx]
            out[2] = (bs - fm) - logZ;       // logp[idx]
            out[3] = logZ - fss / fz;        // entropy
        }
    }
}

// ---------------------------------------------------------------------------
extern "C" void kernel_launch(void* const* d_in, const int* in_sizes, int n_in,
                              void* d_out, int out_size, void* d_ws, size_t ws_size,
                              hipStream_t stream)
{
    const float* x_graph = (const float*)d_in[0];
    const float* x_m     = (const float*)d_in[1];
    const float* x_job   = (const float*)d_in[2];
    const int*   m_ids   = (const int*)d_in[3];
    const int*   job_idx = (const int*)d_in[4];
    const float* W0      = (const float*)d_in[5];
    const float* b0      = (const float*)d_in[6];
    const float* W1      = (const float*)d_in[7];
    const float* b1      = (const float*)d_in[8];
    const float* W2      = (const float*)d_in[9];
    const float* b2      = (const float*)d_in[10];
    float* out = (float*)d_out;

    const int N = in_sizes[3];
    const int M = in_sizes[1] / HID;
    const int J = in_sizes[2] / HID;

    const int tiles = (N + TILE_R - 1) / TILE_R;         // 3125
    const int aTiles = (M + TILE_P - 1) / TILE_P;        // 32
    const int bTiles = (J + TILE_P - 1) / TILE_P;        // 157

    // ws layout (segments 16-B aligned):
    float* ws = (float*)d_ws;
    float* g = ws;                                        // 128 f
    float4* partials = (float4*)(g + HID);                // tiles f4
    int* candIdx = (int*)(partials + tiles);              // GCAP i
    float* candS = (float*)(candIdx + GCAP);              // GCAP f
    int* ncand = (int*)(candS + GCAP);                    // 1 i
    int* donecnt = ncand + 1;                             // 1 i
    unsigned* gmaxU = (unsigned*)(ncand + 2);             // 1 u (+1 pad)
    unsigned short* W1T = (unsigned short*)(ncand + 4);   // HID*HID shorts
    unsigned short* Pbf = W1T + HID * HID;                // (M+J)*HID shorts

    precompute_kernel<<<1 + aTiles + bTiles + 1, 256, 0, stream>>>(
        x_graph, x_m, x_job, W0, b0, W1, g, Pbf, W1T, ncand, donecnt, gmaxU,
        M, J, aTiles, bTiles);
    main_kernel<<<MAIN_GRID, 256, 0, stream>>>(
        m_ids, job_idx, b1, W2, b2, g, Pbf, W1T, x_m, x_job, W0, W1,
        partials, candIdx, candS, ncand, donecnt, gmaxU, out, N, M, tiles);
}

// Round 7
// 162.387 us; speedup vs baseline: 1.1885x; 1.0806x over previous
//
#include <hip/hip_runtime.h>
#include <math.h>

#define HID 128
#define TILE_R 64
#define TILE_P 32          // precompute row tile
#define XS_STRIDE 132      // fp32 staging stride (K1)
#define H0S_STRIDE 136     // bf16 LDS stride in shorts: 136*2B row = 68 dwords == 4 mod 32 banks
#define DELTA 0.05f        // per-score qualify margin (R3/R6-validated)
#define MAIN_GRID 1024     // 4 blocks/CU co-resident persistent main
#define LCAP 128           // per-block candidate cap
#define GCAP 8192          // global candidate cap

typedef short bf16x8 __attribute__((ext_vector_type(8)));
typedef float f32x4 __attribute__((ext_vector_type(4)));

static __device__ __forceinline__ unsigned short f2bf(float f) {
    union { float f; unsigned u; } v; v.f = f;
    unsigned r = v.u + 0x7FFFu + ((v.u >> 16) & 1u);   // RNE
    return (unsigned short)(r >> 16);
}
static __device__ __forceinline__ float bflo(unsigned u) {
    union { unsigned u; float f; } v; v.u = u << 16; return v.f;
}
static __device__ __forceinline__ float bfhi(unsigned u) {
    union { unsigned u; float f; } v; v.u = u & 0xFFFF0000u; return v.f;
}
// monotone float<->uint order map (for atomicMax on float scores)
static __device__ __forceinline__ unsigned f2ord(float f) {
    unsigned b = __float_as_uint(f);
    return (b & 0x80000000u) ? ~b : (b | 0x80000000u);
}
static __device__ __forceinline__ float ord2f(unsigned u) {
    return __uint_as_float((u & 0x80000000u) ? (u ^ 0x80000000u) : ~u);
}

#define FMA4(avc, wv)                         \
    acc[r][0] = fmaf(avc, wv.x, acc[r][0]);   \
    acc[r][1] = fmaf(avc, wv.y, acc[r][1]);   \
    acc[r][2] = fmaf(avc, wv.z, acc[r][2]);   \
    acc[r][3] = fmaf(avc, wv.w, acc[r][3]);

static __device__ __forceinline__ void sm_merge(float& am, float& az, float& ass, int& ai,
                                                float bm, float bz, float bss, int bi)
{
    if (bm > am || (bm == am && bi < ai)) {
        float tm = am, tz = az, ts = ass; int ti = ai;
        am = bm; az = bz; ass = bss; ai = bi;
        bm = tm; bz = tz; bss = ts; bi = ti;
    }
    float f = expf(bm - am);
    az += bz * f;
    ass += (bss + (bm - am) * bz) * f;
}

// ---------------------------------------------------------------------------
// K1: g = x_graph @ W0[0:256] + b0 (fp32); Pbf = bf16 node partials;
//     W1T[n*128+k] = bf16(W1[k][n]).  Block 0 zeroes ncand/donecnt/gmaxU
//     (re-zeroed every graph replay; visible to K2 by stream order).
// ---------------------------------------------------------------------------
__global__ __launch_bounds__(256, 4) void precompute_kernel(
    const float* __restrict__ x_graph,
    const float* __restrict__ x_m,
    const float* __restrict__ x_job,
    const float* __restrict__ W0,
    const float* __restrict__ b0,
    const float* __restrict__ W1,
    float* __restrict__ g,
    unsigned short* __restrict__ Pbf,
    unsigned short* __restrict__ W1T,
    int* __restrict__ ncand,
    int* __restrict__ donecnt,
    unsigned* __restrict__ gmaxU,
    int M, int J, int aTiles, int bTiles)
{
    const int t = threadIdx.x;
    const int bid = blockIdx.x;

    if (bid == 0) {
        if (t == 0) { *ncand = 0; *donecnt = 0; *gmaxU = 0u; }  // reset each replay
        __shared__ float xg[2 * HID];
        if (t < HID) { xg[t] = x_graph[t]; xg[t + HID] = x_graph[t + HID]; }
        __syncthreads();
        if (t < HID) {
            float acc = b0[t];
            #pragma unroll 8
            for (int k = 0; k < 2 * HID; ++k)
                acc = fmaf(xg[k], W0[k * HID + t], acc);
            g[t] = acc;
        }
        return;
    }
    if (bid == 1 + aTiles + bTiles) {
        for (int e = t; e < HID * HID; e += 256) {
            int n = e >> 7, k = e & 127;
            W1T[e] = f2bf(W1[k * HID + n]);
        }
        return;
    }

    const int tb = bid - 1;
    const float* X;
    const float* W;
    int r0, nr, dstBase;
    if (tb < aTiles) {
        r0 = tb * TILE_P;
        nr = min(TILE_P, M - r0);
        X = x_m + (size_t)r0 * HID;
        W = W0 + 2 * HID * HID;
        dstBase = r0;
    } else {
        int jb = tb - aTiles;
        r0 = jb * TILE_P;
        nr = min(TILE_P, J - r0);
        X = x_job + (size_t)r0 * HID;
        W = W0 + 3 * HID * HID;
        dstBase = M + r0;
    }

    __shared__ float xs[TILE_P * XS_STRIDE];
    {
        int row = t >> 3;
        int e = t & 7;
        #pragma unroll
        for (int u = 0; u < 4; ++u) {
            int c = e * 16 + u * 4;
            float4 v = (row < nr) ? *(const float4*)(X + row * HID + c)
                                  : make_float4(0.f, 0.f, 0.f, 0.f);
            *(float4*)&xs[row * XS_STRIDE + c] = v;
        }
    }
    __syncthreads();

    const int w = t >> 6;
    const int l = t & 63;
    const int tc = l & 7;
    const int tr = l >> 3;
    const int c0 = w * 32 + tc * 4;

    float acc[4][4];
    #pragma unroll
    for (int r = 0; r < 4; ++r)
        #pragma unroll
        for (int c = 0; c < 4; ++c) acc[r][c] = 0.0f;

    #pragma unroll 2
    for (int k0 = 0; k0 < HID; k0 += 4) {
        float4 w0v = *(const float4*)(W + (k0 + 0) * HID + c0);
        float4 w1v = *(const float4*)(W + (k0 + 1) * HID + c0);
        float4 w2m = *(const float4*)(W + (k0 + 2) * HID + c0);
        float4 w3v = *(const float4*)(W + (k0 + 3) * HID + c0);
        #pragma unroll
        for (int r = 0; r < 4; ++r) {
            float4 a = *(const float4*)&xs[(r * 8 + tr) * XS_STRIDE + k0];
            FMA4(a.x, w0v)
            FMA4(a.y, w1v)
            FMA4(a.z, w2m)
            FMA4(a.w, w3v)
        }
    }

    #pragma unroll
    for (int r = 0; r < 4; ++r) {
        int row = r * 8 + tr;
        if (row < nr) {
            unsigned lo0 = (unsigned)f2bf(acc[r][0]) | ((unsigned)f2bf(acc[r][1]) << 16);
            unsigned lo1 = (unsigned)f2bf(acc[r][2]) | ((unsigned)f2bf(acc[r][3]) << 16);
            uint2 pk = make_uint2(lo0, lo1);
            *(uint2*)(Pbf + (size_t)(dstBase + row) * HID + c0) = pk;
        }
    }
}

// ---------------------------------------------------------------------------
// K2 (R19): persistent reg-B main; LOCAL-rmax harvest (idx + bf16 score);
//   post-loop: ONE atomicMax publish per block (R6's per-tile atomicMax on a
//   single hot line cost ~45us -- removed), stale-gmax filter (stale <= gmax
//   -> superset kept -> exact winner preserved), parallel 4-wave exact
//   rescore of survivors, one-atomic flush, last-done-block tiny finalize.
// ---------------------------------------------------------------------------
__global__ __launch_bounds__(256, 4) void main_kernel(
    const int* __restrict__ m_ids,
    const int* __restrict__ job_idx,
    const float* __restrict__ b1,
    const float* __restrict__ W2,
    const float* __restrict__ b2,
    const float* __restrict__ g,
    const unsigned short* __restrict__ Pbf,
    const unsigned short* __restrict__ W1T,
    const float* __restrict__ x_m,
    const float* __restrict__ x_job,
    const float* __restrict__ W0,
    const float* __restrict__ W1,
    float4* __restrict__ partials,
    int* __restrict__ candIdx,
    float* __restrict__ candS,
    int* __restrict__ ncand,
    int* __restrict__ donecnt,
    unsigned* __restrict__ gmaxU,
    float* __restrict__ out,
    int N, int M, int tiles)
{
    __shared__ __align__(16) short h0s[TILE_R * H0S_STRIDE];
    __shared__ float sred[4 * TILE_R];
    __shared__ int lcand[LCAP];
    __shared__ float lcs[LCAP];
    __shared__ int surv[LCAP];
    __shared__ float scs[LCAP];
    __shared__ int lcnt;
    __shared__ int scount;
    __shared__ float gestS;
    __shared__ int lastFlag;

    const int t = threadIdx.x;
    const int l = t & 63;
    const int w = t >> 6;
    const int quad = l >> 4;
    const int mrow = l & 15;

    if (t == 0) { lcnt = 0; scount = 0; }

    // ---- B fragments + epilogue constants: once per block ----
    bf16x8 bfr[2][4];
    {
        const unsigned short* wb = W1T + (size_t)(w * 32 + mrow) * HID + quad * 8;
        #pragma unroll
        for (int nt = 0; nt < 2; ++nt)
            #pragma unroll
            for (int kc = 0; kc < 4; ++kc)
                bfr[nt][kc] = *(const bf16x8*)(wb + nt * 16 * HID + kc * 32);
    }
    const float b1v0 = b1[w * 32 + mrow];
    const float b1v1 = b1[w * 32 + 16 + mrow];
    const float w2v0 = W2[w * 32 + mrow];
    const float w2v1 = W2[w * 32 + 16 + mrow];
    const float b2v = b2[0];

    float rmax = -1e30f;   // block-local running max (wave 0)

    for (int tile = blockIdx.x; tile < tiles; tile += MAIN_GRID) {
        const int row0 = tile * TILE_R;

        // ---- stage h0 (bf16): thread t -> row t/4, 32-col quarter t%4 ----
        {
            int row = t >> 2;
            int q = t & 3;
            int grow = row0 + row;
            int gr = (grow < N) ? grow : (N - 1);
            int m = m_ids[gr];
            int j = job_idx[gr];
            const unsigned short* pm = Pbf + (size_t)m * HID + q * 32;
            const unsigned short* pj = Pbf + (size_t)(M + j) * HID + q * 32;
            const float* gp = g + q * 32;
            short* dst = &h0s[row * H0S_STRIDE + q * 32];
            #pragma unroll
            for (int u = 0; u < 4; ++u) {
                uint4 mv = *(const uint4*)(pm + u * 8);
                uint4 jv = *(const uint4*)(pj + u * 8);
                float4 g0 = *(const float4*)(gp + u * 8);
                float4 g1 = *(const float4*)(gp + u * 8 + 4);
                float h0v = fmaxf(bflo(mv.x) + bflo(jv.x) + g0.x, 0.f);
                float h1v = fmaxf(bfhi(mv.x) + bfhi(jv.x) + g0.y, 0.f);
                float h2v = fmaxf(bflo(mv.y) + bflo(jv.y) + g0.z, 0.f);
                float h3v = fmaxf(bfhi(mv.y) + bfhi(jv.y) + g0.w, 0.f);
                float h4v = fmaxf(bflo(mv.z) + bflo(jv.z) + g1.x, 0.f);
                float h5v = fmaxf(bfhi(mv.z) + bfhi(jv.z) + g1.y, 0.f);
                float h6v = fmaxf(bflo(mv.w) + bflo(jv.w) + g1.z, 0.f);
                float h7v = fmaxf(bfhi(mv.w) + bfhi(jv.w) + g1.w, 0.f);
                uint4 pk;
                pk.x = (unsigned)f2bf(h0v) | ((unsigned)f2bf(h1v) << 16);
                pk.y = (unsigned)f2bf(h2v) | ((unsigned)f2bf(h3v) << 16);
                pk.z = (unsigned)f2bf(h4v) | ((unsigned)f2bf(h5v) << 16);
                pk.w = (unsigned)f2bf(h6v) | ((unsigned)f2bf(h7v) << 16);
                *(uint4*)(dst + u * 8) = pk;
            }
        }
        __syncthreads();                       // barrier 1: h0s ready

        // ---- MFMA: 4 m-tiles x 2 n-tiles; A from LDS, B from registers ----
        f32x4 acc[4][2];
        #pragma unroll
        for (int mt = 0; mt < 4; ++mt) {
            f32x4 z = {0.f, 0.f, 0.f, 0.f};
            acc[mt][0] = z;
            acc[mt][1] = z;
        }
        #pragma unroll
        for (int mt = 0; mt < 4; ++mt) {
            const short* ab = &h0s[(mt * 16 + mrow) * H0S_STRIDE + quad * 8];
            #pragma unroll
            for (int kc = 0; kc < 4; ++kc) {
                bf16x8 af = *(const bf16x8*)(ab + kc * 32);
                acc[mt][0] = __builtin_amdgcn_mfma_f32_16x16x32_bf16(af, bfr[0][kc], acc[mt][0], 0, 0, 0);
                acc[mt][1] = __builtin_amdgcn_mfma_f32_16x16x32_bf16(af, bfr[1][kc], acc[mt][1], 0, 0, 0);
            }
        }

        // ---- epilogue: relu+b1, dot W2; reduce over 16 cols (mrow lanes) ----
        #pragma unroll
        for (int mt = 0; mt < 4; ++mt) {
            float p[4];
            #pragma unroll
            for (int i = 0; i < 4; ++i) {
                p[i] = fmaxf(acc[mt][0][i] + b1v0, 0.f) * w2v0
                     + fmaxf(acc[mt][1][i] + b1v1, 0.f) * w2v1;
            }
            #pragma unroll
            for (int off = 1; off < 16; off <<= 1) {
                #pragma unroll
                for (int i = 0; i < 4; ++i)
                    p[i] += __shfl_xor(p[i], off);
            }
            if (mrow == 0) {
                int rb = mt * 16 + quad * 4;
                sred[w * TILE_R + rb + 0] = p[0];
                sred[w * TILE_R + rb + 1] = p[1];
                sred[w * TILE_R + rb + 2] = p[2];
                sred[w * TILE_R + rb + 3] = p[3];
            }
        }
        __syncthreads();                       // barrier 2: sred ready; h0s free

        // ---- wave 0: combine col-groups, softmax partial, harvest ----
        if (t < 64) {
            int grow = row0 + t;
            bool valid = grow < N;
            float s = sred[t] + sred[64 + t] + sred[128 + t] + sred[192 + t] + b2v;
            if (!valid) s = -1e30f;

            float mmax = s;
            int midx = grow;
            #pragma unroll
            for (int off = 1; off < 64; off <<= 1) {
                float om = __shfl_xor(mmax, off);
                int oi = __shfl_xor(midx, off);
                if (om > mmax || (om == mmax && oi < midx)) { mmax = om; midx = oi; }
            }
            float d = s - mmax;
            float e = expf(d);
            float z = e;
            float ss = d * e;
            #pragma unroll
            for (int off = 1; off < 64; off <<= 1) {
                z += __shfl_xor(z, off);
                ss += __shfl_xor(ss, off);
            }
            if (t == 0) partials[tile] = make_float4(mmax, z, ss, (float)midx);

            // LOCAL-rmax harvest (no global atomics in-loop): superset of
            // {s >= gmax-DELTA} since rmax <= gmax. Store idx + bf16 score.
            rmax = fmaxf(rmax, mmax);
            unsigned long long qm = __ballot(valid && (s >= rmax - DELTA));
            if (qm) {
                int cnt = __popcll(qm);
                int rank = __popcll(qm & ((1ull << t) - 1ull));
                int lb;
                if (t == 0) lb = atomicAdd(&lcnt, cnt);   // LDS atomic (wave 0 only)
                lb = __shfl(lb, 0);
                if ((qm >> t) & 1ull) {
                    int p = lb + rank;
                    if (p < LCAP) { lcand[p] = grow; lcs[p] = s; }
                }
            }
        }
        // sred reads above precede next iteration's barrier 1; next writes
        // happen after it -> no WAR hazard. lcand/lcs/lcnt: wave 0 only.
    }

    // ---- R19: ONE atomicMax publish; stale-global filter; parallel rescore ----
    __syncthreads();                       // lcand/lcs/lcnt -> all waves
    if (t == 0) {
        unsigned old = atomicMax(gmaxU, f2ord(rmax));   // one per block, staggered
        gestS = fmaxf(rmax, ord2f(old));   // est <= final gmax -> filter keeps superset
    }
    __syncthreads();
    const float cut = gestS - DELTA;

    // wave 0: filter+compact survivors (ballot-rank, <=2 rounds of 64)
    if (t < 64) {
        int cnt = min(lcnt, LCAP);
        for (int base = 0; base < cnt; base += 64) {
            int c = base + t;
            bool act = (c < cnt) && (lcs[c] >= cut);
            unsigned long long qm = __ballot(act);
            int nb = scount;               // wave-coherent read (wave 0 only)
            int rank = __popcll(qm & ((1ull << t) - 1ull));
            if (act) surv[nb + rank] = lcand[c];
            if (t == 0) scount = nb + __popcll(qm);
        }
    }
    __syncthreads();
    const int ns = min(scount, LCAP);

    // all 4 waves: exact fp32 rescore of survivors
    for (int c = w; c < ns; c += 4) {
        int gr = surv[c];
        int mm = m_ids[gr];
        int jj = job_idx[gr];
        const float* xm = x_m + (size_t)mm * HID;
        const float* xj = x_job + (size_t)jj * HID;
        const float* wm = W0 + 2 * HID * HID;
        const float* wj = W0 + 3 * HID * HID;
        float a0 = g[l], a1 = g[l + 64];
        for (int k = 0; k < HID; ++k) {
            float xmk = xm[k];
            float xjk = xj[k];
            a0 = fmaf(xmk, wm[k * HID + l], a0);
            a1 = fmaf(xmk, wm[k * HID + l + 64], a1);
            a0 = fmaf(xjk, wj[k * HID + l], a0);
            a1 = fmaf(xjk, wj[k * HID + l + 64], a1);
        }
        a0 = fmaxf(a0, 0.f);
        a1 = fmaxf(a1, 0.f);
        float acc0 = 0.f, acc1 = 0.f;
        for (int k = 0; k < 64; ++k) {
            float h = __shfl(a0, k);
            acc0 = fmaf(h, W1[k * HID + l], acc0);
            acc1 = fmaf(h, W1[k * HID + l + 64], acc1);
        }
        for (int k = 0; k < 64; ++k) {
            float h = __shfl(a1, k);
            acc0 = fmaf(h, W1[(k + 64) * HID + l], acc0);
            acc1 = fmaf(h, W1[(k + 64) * HID + l + 64], acc1);
        }
        float p = fmaxf(acc0 + b1[l], 0.f) * W2[l]
                + fmaxf(acc1 + b1[l + 64], 0.f) * W2[l + 64];
        #pragma unroll
        for (int off = 1; off < 64; off <<= 1)
            p += __shfl_xor(p, off);
        if (l == 0) scs[c] = p + b2v;     // EXACT score
    }
    __syncthreads();

    // ---- flush survivors: one staggered device atomic, burst copy ----
    if (t < 64 && ns > 0) {
        int gb;
        if (t == 0) gb = atomicAdd(ncand, ns);            // device-scope
        gb = __shfl(gb, 0);
        for (int c = t; c < ns; c += 64) {
            int p = gb + c;
            if (p < GCAP) { candIdx[p] = surv[c]; candS[p] = scs[c]; }
        }
    }

    // ---- arrival: last-done block runs the tiny finalize ----
    __syncthreads();            // drain all waves' stores
    if (t == 0) {
        __threadfence();        // release: publish partials/cand* device-wide
        int v = __hip_atomic_fetch_add(donecnt, 1, __ATOMIC_ACQ_REL,
                                       __HIP_MEMORY_SCOPE_AGENT);
        lastFlag = (v == (int)gridDim.x - 1);
    }
    __syncthreads();
    if (!lastFlag) return;
    __threadfence();            // acquire: see all other blocks' writes

    // ================= finalize: merge partials + max over exact cands ====
    {
        __shared__ float4 wred[4];
        __shared__ int widx[4];
        __shared__ float frs[4];
        __shared__ int fri[4];

        float fm = -1e30f, fz = 0.f, fss = 0.f;
        int fidx = 0x7fffffff;
        for (int i = t; i < tiles; i += 256) {
            float4 p = partials[i];
            sm_merge(fm, fz, fss, fidx, p.x, p.y, p.z, (int)p.w);
        }
        #pragma unroll
        for (int off = 1; off < 64; off <<= 1) {
            float om = __shfl_xor(fm, off);
            float oz = __shfl_xor(fz, off);
            float os = __shfl_xor(fss, off);
            int oi = __shfl_xor(fidx, off);
            sm_merge(fm, fz, fss, fidx, om, oz, os, oi);
        }
        if (l == 0) { wred[w] = make_float4(fm, fz, fss, 0.f); widx[w] = fidx; }

        // exact argmax over candidate superset (identical winner/bs to the
        // old filter+rescore path -- superset argument in K2 header)
        float bs = -1e30f;
        int bi = 0x7fffffff;
        const int nc = min(*ncand, GCAP);
        for (int c = t; c < nc; c += 256) {
            float s = candS[c];
            int gi = candIdx[c];
            if (s > bs || (s == bs && gi < bi)) { bs = s; bi = gi; }
        }
        #pragma unroll
        for (int off = 1; off < 64; off <<= 1) {
            float os = __shfl_xor(bs, off);
            int oi = __shfl_xor(bi, off);
            if (os > bs || (os == bs && oi < bi)) { bs = os; bi = oi; }
        }
        if (l == 0) { frs[w] = bs; fri[w] = bi; }
        __syncthreads();

        if (t == 0) {
            for (int i = 1; i < 4; ++i)
                sm_merge(fm, fz, fss, fidx, wred[i].x, wred[i].y, wred[i].z, widx[i]);
            for (int i = 1; i < 4; ++i)
                if (frs[i] > bs || (frs[i] == bs && fri[i] < bi)) { bs = frs[i]; bi = fri[i]; }
            float logZ = logf(fz);
            out[0] = (float)bi;              // exact argmax
            out[1] = expf(bs - fm) / fz;     // probs[idx]
            out[2] = (bs - fm) - logZ;       // logp[idx]
            out[3] = logZ - fss / fz;        // entropy
        }
    }
}

// ---------------------------------------------------------------------------
extern "C" void kernel_launch(void* const* d_in, const int* in_sizes, int n_in,
                              void* d_out, int out_size, void* d_ws, size_t ws_size,
                              hipStream_t stream)
{
    const float* x_graph = (const float*)d_in[0];
    const float* x_m     = (const float*)d_in[1];
    const float* x_job   = (const float*)d_in[2];
    const int*   m_ids   = (const int*)d_in[3];
    const int*   job_idx = (const int*)d_in[4];
    const float* W0      = (const float*)d_in[5];
    const float* b0      = (const float*)d_in[6];
    const float* W1      = (const float*)d_in[7];
    const float* b1      = (const float*)d_in[8];
    const float* W2      = (const float*)d_in[9];
    const float* b2      = (const float*)d_in[10];
    float* out = (float*)d_out;

    const int N = in_sizes[3];
    const int M = in_sizes[1] / HID;
    const int J = in_sizes[2] / HID;

    const int tiles = (N + TILE_R - 1) / TILE_R;         // 3125
    const int aTiles = (M + TILE_P - 1) / TILE_P;        // 32
    const int bTiles = (J + TILE_P - 1) / TILE_P;        // 157

    // ws layout (segments 16-B aligned):
    float* ws = (float*)d_ws;
    float* g = ws;                                        // 128 f
    float4* partials = (float4*)(g + HID);                // tiles f4
    int* candIdx = (int*)(partials + tiles);              // GCAP i
    float* candS = (float*)(candIdx + GCAP);              // GCAP f
    int* ncand = (int*)(candS + GCAP);                    // 1 i
    int* donecnt = ncand + 1;                             // 1 i
    unsigned* gmaxU = (unsigned*)(ncand + 2);             // 1 u (+1 pad)
    unsigned short* W1T = (unsigned short*)(ncand + 4);   // HID*HID shorts
    unsigned short* Pbf = W1T + HID * HID;                // (M+J)*HID shorts

    precompute_kernel<<<1 + aTiles + bTiles + 1, 256, 0, stream>>>(
        x_graph, x_m, x_job, W0, b0, W1, g, Pbf, W1T, ncand, donecnt, gmaxU,
        M, J, aTiles, bTiles);
    main_kernel<<<MAIN_GRID, 256, 0, stream>>>(
        m_ids, job_idx, b1, W2, b2, g, Pbf, W1T, x_m, x_job, W0, W1,
        partials, candIdx, candS, ncand, donecnt, gmaxU, out, N, M, tiles);
}